// Round 1
// 276.944 us; speedup vs baseline: 1.0438x; 1.0438x over previous
//
#include <hip/hip_runtime.h>

#define THRESH 0.05f

typedef __attribute__((ext_vector_type(4)))  int   int32x4;
typedef __attribute__((ext_vector_type(16))) int   int32x16;
typedef __attribute__((ext_vector_type(4)))  float floatx4;

// ---------------------------------------------------------------------------
// Kernel 1: quantize weight [1024,1024] fp32 -> int8 {-1,0,+1} in FRAGMENT
// ORDER for the mfma_i32_32x32x32_i8 B-operand:
//   1 KB block per (nb,k):  wqf[((nb*32 + k)*64 + lane)*16 + byte]
//   lane l supplies w[col = nb*32 + (l&31)][k*32 + (l>>5)*16 .. +16)
// so a wave's B-fragment load is one 1 KB lane-contiguous dwordx4 burst.
// ---------------------------------------------------------------------------
__global__ __launch_bounds__(256) void quant_w_kernel(const float* __restrict__ w,
                                                      signed char* __restrict__ wqf) {
    int c = blockIdx.x * 256 + threadIdx.x;   // 16-byte chunk id, 0..65535
    int l  = c & 63;
    int k  = (c >> 6) & 31;
    int nb = c >> 11;
    int col   = nb * 32 + (l & 31);
    int kbase = k * 32 + (l >> 5) * 16;
    const float* src = w + col * 1024 + kbase;
    signed char q[16];
    #pragma unroll
    for (int j = 0; j < 4; ++j) {
        float4 f = *(const float4*)(src + j * 4);
        q[j * 4 + 0] = (signed char)((f.x >= THRESH) - (f.x <= -THRESH));
        q[j * 4 + 1] = (signed char)((f.y >= THRESH) - (f.y <= -THRESH));
        q[j * 4 + 2] = (signed char)((f.z >= THRESH) - (f.z <= -THRESH));
        q[j * 4 + 3] = (signed char)((f.w >= THRESH) - (f.w <= -THRESH));
    }
    *(int32x4*)(wqf + (size_t)c * 16) = *(const int32x4*)q;
}

// ---------------------------------------------------------------------------
// Kernel 2: slab-resident ternary GEMM, 32x32x32 i8 MFMA (K=32/instr).
// Block = 256 threads (4 waves) x 32-row slab x all 1024 cols; 32 KB LDS,
// grid 1024 -> 4 blocks/CU, 16 waves/CU.
// vs previous 16x16x64 version:
//  * one af ds_read_b128 now feeds TWO 32x32 MFMAs (two adjacent col-tiles)
//    covering K=32 -> LDS reads per wave drop 4x (512 -> 128). LDS pipe was
//    ~55 us/CU of the 120 us (2.1M b128 x 12cyc + 8.4M conflict cyc).
//  * UNSWAPPED operands: D col = lane&31 -> epilogue store instructions
//    write 2 rows x 128 B contiguous lines (was 16 B per lane at 4 KB row
//    stride) -> kills the 179/135 MB write amplification.
//  * B traffic per MFMA halves (1 KB fragment -> 32K MACs).
// ---------------------------------------------------------------------------
__global__ __launch_bounds__(256, 4) void tern_gemm_kernel(const float* __restrict__ x,
                                                           const signed char* __restrict__ wqf,
                                                           float* __restrict__ out) {
    __shared__ __attribute__((aligned(16))) signed char a_lds[32 * 1024];
    const int tid = threadIdx.x;
    const long rowbase = (long)blockIdx.x * 32;

    // ---- Phase 1: stage + quantize x slab (32 rows x 1024 K) ----
    // Row layout: 64 16B-chunks, stored at chunk' = chunk ^ (row&7) (XOR
    // swizzle; bijective per row, matches the af read below).
    #pragma unroll
    for (int i = 0; i < 8; ++i) {
        int c   = tid + i * 256;   // chunk id 0..2047
        int row = c >> 6;          // 64 chunks per row
        int cir = c & 63;          // chunk-in-row
        const floatx4* src = (const floatx4*)(x + (rowbase + row) * 1024 + cir * 16);
        signed char q[16];
        #pragma unroll
        for (int j = 0; j < 4; ++j) {
            floatx4 f = __builtin_nontemporal_load(src + j);
            #pragma unroll
            for (int e = 0; e < 4; ++e)
                q[j * 4 + e] = (signed char)((f[e] >= THRESH) - (f[e] <= -THRESH));
        }
        int swz = (cir ^ (row & 7)) * 16;
        *(int32x4*)(a_lds + row * 1024 + swz) = *(const int32x4*)q;
    }
    __syncthreads();

    // ---- Phase 2: compute ----
    const int wave  = tid >> 6;    // 0..3
    const int lane  = tid & 63;
    const int l31   = lane & 31;
    const int hi    = lane >> 5;   // which K-half of the 32-byte chunk
    const int ex    = l31 & 7;     // row's XOR key
    const int abase = l31 * 1024;  // af row base (row = l31)

    for (int ot = 0; ot < 4; ++ot) {
        // wave owns 64 cols = two adjacent 32-col B tiles nb0, nb0+1
        const int nb0 = ot * 8 + wave * 2;
        const signed char* bp = wqf + (size_t)nb0 * 32768 + lane * 16;

        int32x16 acc0 = {0,0,0,0,0,0,0,0,0,0,0,0,0,0,0,0};
        int32x16 acc1 = {0,0,0,0,0,0,0,0,0,0,0,0,0,0,0,0};

        #pragma unroll
        for (int ks = 0; ks < 8; ++ks) {
            // B burst: 4 K-steps x 2 tiles = 8 independent coalesced 1 KB
            // loads (one L2 latency). 32 regs -> fits AGPR side w/ acc.
            int32x4 b0[4], b1[4];
            #pragma unroll
            for (int j = 0; j < 4; ++j) {
                b0[j] = *(const int32x4*)(bp + (size_t)(ks * 4 + j) * 1024);
                b1[j] = *(const int32x4*)(bp + 32768 + (size_t)(ks * 4 + j) * 1024);
            }
            __builtin_amdgcn_sched_barrier(0);  // keep the burst ahead of MFMAs
            #pragma unroll
            for (int j = 0; j < 4; ++j) {
                int k2 = (ks * 4 + j) * 2 + hi;     // 16B chunk-in-row index
                int32x4 af = *(const int32x4*)(a_lds + abase + ((k2 ^ ex) * 16));
                // unswapped: D col = lane&31 = out col (B idx),
                //            D row = (r&3)+8*(r>>2)+4*hi = out row (A idx)
                acc0 = __builtin_amdgcn_mfma_i32_32x32x32_i8(af, b0[j], acc0, 0, 0, 0);
                acc1 = __builtin_amdgcn_mfma_i32_32x32x32_i8(af, b1[j], acc1, 0, 0, 0);
            }
        }

        // ---- epilogue: scalar nt stores, 32 lanes = 128 B contiguous/row ----
        const int cb = ot * 256 + wave * 64 + l31;
        #pragma unroll
        for (int r = 0; r < 16; ++r) {
            int row = (r & 3) + 8 * (r >> 2) + 4 * hi;
            float* o = out + (rowbase + row) * 1024 + cb;
            __builtin_nontemporal_store((float)acc0[r], o);
            __builtin_nontemporal_store((float)acc1[r], o + 32);
        }
    }
}

extern "C" void kernel_launch(void* const* d_in, const int* in_sizes, int n_in,
                              void* d_out, int out_size, void* d_ws, size_t ws_size,
                              hipStream_t stream) {
    const float* x = (const float*)d_in[0];      // [32768, 1024] fp32
    const float* w = (const float*)d_in[1];      // [1024, 1024] fp32
    float* out = (float*)d_out;                  // [32768, 1024] fp32
    signed char* wqf = (signed char*)d_ws;       // 1 MB int8 scratch (fragment order)

    quant_w_kernel<<<dim3(256), dim3(256), 0, stream>>>(w, wqf);
    // 32768 rows / 32 = 1024 blocks (4 per CU), 4 waves each
    tern_gemm_kernel<<<dim3(1024), dim3(256), 0, stream>>>(x, wqf, out);
}